// Round 2
// baseline (20843.391 us; speedup 1.0000x reference)
//
#include <hip/hip_runtime.h>
#include <cmath>

static constexpr int   Bb     = 16;
static constexpr int   Nn     = 1024;
static constexpr int   Mm     = 1024;
static constexpr int   Dd     = 64;
static constexpr int   MAXIT  = 100;
static constexpr float THRESH = 1e-4f;
// (1/eps) * log2(e): scale (v - C) into log2 domain
static constexpr float SCALE2 = 144.26950408889634f;
// eps * ln(2)
static constexpr float EPSLN2 = 0.006931471805599453f;
// eps * log(1/1024 + 1e-8)   (log_a == log_b since N == M)
static constexpr float UAB    = -0.06931461565651f;

__device__ __forceinline__ void lse_acc(float& m, float& s, float a) {
    float nm = fmaxf(m, a);
    s = s * exp2f(m - nm) + exp2f(a - nm);
    m = nm;
}
__device__ __forceinline__ void lse_comb(float& m, float& s, float mo, float so) {
    float nm = fmaxf(m, mo);
    s = s * exp2f(m - nm) + so * exp2f(mo - nm);
    m = nm;
}

//==================== init: transpose y -> yT[b][d][j]; zero u,v,dslots,out
__global__ __launch_bounds__(256)
void init_kernel(const float* __restrict__ y, float* __restrict__ yT,
                 float* __restrict__ u, float* __restrict__ v,
                 float* __restrict__ dslots, float* __restrict__ out)
{
    __shared__ float sm[64 * 65];
    const int tid = threadIdx.x;
    const int bid = blockIdx.x;
    if (bid < 256) {
        const int b  = bid >> 4;
        const int j0 = (bid & 15) << 6;
        const float4* src = (const float4*)(y + (size_t)(b * Mm + j0) * Dd);
#pragma unroll
        for (int k = 0; k < 4; ++k) {
            const int f4 = tid + (k << 8);
            float4 w = src[f4];
            const int f = f4 << 2;
            float* dst = sm + (f >> 6) * 65 + (f & 63);
            dst[0] = w.x; dst[1] = w.y; dst[2] = w.z; dst[3] = w.w;
        }
        __syncthreads();
        const int jj = tid & 63;
        const int db = tid >> 6;
#pragma unroll
        for (int k = 0; k < 16; ++k) {
            const int d = db + (k << 2);
            yT[(size_t)(b * Dd + d) * Mm + j0 + jj] = sm[jj * 65 + d];
        }
    } else if (bid == 256) {
        for (int k = tid; k < Bb * Nn; k += 256) u[k] = 0.f;
    } else if (bid == 257) {
        for (int k = tid; k < Bb * Mm; k += 256) v[k] = 0.f;
    } else {
        for (int k = tid; k < MAXIT * 64; k += 256) dslots[k] = 0.f;
        if (tid < Bb) out[tid] = 0.f;
    }
}

//==================== build C (and CT): C = ||x||^2 + ||y||^2 - 2 x.y
template <bool USE_CT>
__global__ __launch_bounds__(256)
void cbuild_kernel(const float* __restrict__ x, const float* __restrict__ yT,
                   float* __restrict__ C, float* __restrict__ CT)
{
    __shared__ float sm[2080];
    const int tid = threadIdx.x;
    const int t   = blockIdx.x;     // 2048 tiles
    const int b   = t >> 7;
    const int rm  = t & 127;
    const int i0  = (rm >> 2) << 5;   // 32-row tile
    const int j0  = (rm & 3) << 8;    // 256-col tile
    float* xs2 = sm;                  // 2048: -2*x tile
    float* xn  = sm + 2048;           // 32: x row norms
    const float4* xsrc = (const float4*)(x + (size_t)(b * Nn + i0) * Dd);
#pragma unroll
    for (int k = 0; k < 2; ++k) {
        const int f4 = tid + (k << 8);
        float4 w = xsrc[f4];
        float* dst = xs2 + (f4 << 2);
        dst[0] = -2.f * w.x; dst[1] = -2.f * w.y;
        dst[2] = -2.f * w.z; dst[3] = -2.f * w.w;
    }
    __syncthreads();
    if (tid < 32) {
        float a = 0.f;
        for (int d = 0; d < 64; ++d) { float q = xs2[tid * 64 + d]; a = fmaf(q, q, a); }
        xn[tid] = 0.25f * a;   // (-2x)^2/4 = x^2
    }
    __syncthreads();
    float acc[32];
#pragma unroll
    for (int ii = 0; ii < 32; ++ii) acc[ii] = 0.f;
    float yn = 0.f;
    const float* yTb = yT + (size_t)b * Dd * Mm + j0 + tid;
    for (int d4 = 0; d4 < 64; d4 += 4) {
        const float y0 = yTb[(size_t)(d4 + 0) * Mm];
        const float y1 = yTb[(size_t)(d4 + 1) * Mm];
        const float y2 = yTb[(size_t)(d4 + 2) * Mm];
        const float y3 = yTb[(size_t)(d4 + 3) * Mm];
        yn = fmaf(y0, y0, yn); yn = fmaf(y1, y1, yn);
        yn = fmaf(y2, y2, yn); yn = fmaf(y3, y3, yn);
#pragma unroll
        for (int ii = 0; ii < 32; ++ii) {
            const float4 xq = *(const float4*)(xs2 + ii * 64 + d4);
            acc[ii] = fmaf(xq.x, y0, acc[ii]);
            acc[ii] = fmaf(xq.y, y1, acc[ii]);
            acc[ii] = fmaf(xq.z, y2, acc[ii]);
            acc[ii] = fmaf(xq.w, y3, acc[ii]);
        }
    }
#pragma unroll
    for (int ii = 0; ii < 32; ++ii) acc[ii] += xn[ii] + yn;
    float* Cout = C + (size_t)(b * Nn + i0) * Mm + j0 + tid;
#pragma unroll
    for (int ii = 0; ii < 32; ++ii) Cout[(size_t)ii * Mm] = acc[ii];
    if constexpr (USE_CT) {
        float* CTout = CT + (size_t)(b * Mm + j0 + tid) * Nn + i0;
#pragma unroll
        for (int ii = 0; ii < 32; ii += 4)
            *(float4*)(CTout + ii) =
                make_float4(acc[ii], acc[ii + 1], acc[ii + 2], acc[ii + 3]);
    }
}

//==================== one half-sweep: dst_i = UAB - eps*lse_j((src_j - Cmat_ij)/eps)
// Cmat row-major for this phase (C for u-update, CT for v-update).
// One wave per row; two-pass lse (row max, then single exp2 per element).
__global__ __launch_bounds__(256)
void sweep_row(const float* __restrict__ Cmat, const float* __restrict__ src,
               float* __restrict__ dst, float* __restrict__ dslots, int it)
{
    const int tid  = threadIdx.x;
    const int lane = tid & 63;
    const int wv   = tid >> 6;
    const int row  = (blockIdx.x << 2) | wv;    // 0..16383  (= b*1024 + i)
    const int b    = row >> 10;

    if (it > 0) {   // frozen? deterministic sum of previous iteration's diff
        float tv = dslots[((it - 1) << 6) + lane];
#pragma unroll
        for (int off = 32; off; off >>= 1) tv += __shfl_xor(tv, off, 64);
        if (tv * (1.f / 16.f) < THRESH) return;
    }

    const float4* s4 = (const float4*)(src + (b << 10));
    const float4* c4 = (const float4*)(Cmat + ((size_t)row << 10));
    float a[16];
    float m = -INFINITY;
#pragma unroll
    for (int q = 0; q < 4; ++q) {
        const float4 c = c4[lane + (q << 6)];
        const float4 s = s4[lane + (q << 6)];
        a[4 * q + 0] = (s.x - c.x) * SCALE2;
        a[4 * q + 1] = (s.y - c.y) * SCALE2;
        a[4 * q + 2] = (s.z - c.z) * SCALE2;
        a[4 * q + 3] = (s.w - c.w) * SCALE2;
        m = fmaxf(m, fmaxf(fmaxf(a[4 * q + 0], a[4 * q + 1]),
                           fmaxf(a[4 * q + 2], a[4 * q + 3])));
    }
#pragma unroll
    for (int off = 32; off; off >>= 1) m = fmaxf(m, __shfl_xor(m, off, 64));
    float ssum = 0.f;
#pragma unroll
    for (int k = 0; k < 16; ++k) ssum += exp2f(a[k] - m);
#pragma unroll
    for (int off = 32; off; off >>= 1) ssum += __shfl_xor(ssum, off, 64);
    if (lane == 0) {
        const float dn = UAB - EPSLN2 * (m + log2f(ssum));
        float* dp = dst + row;
        const float dd = fabsf(dn - *dp);
        *dp = dn;
        atomicAdd(dslots + (it << 6) + (row & 63), dd);
    }
}

//==================== fallback v-update via column reads of C (no CT buffer)
__global__ __launch_bounds__(256)
void sweep_col(const float* __restrict__ C, const float* __restrict__ u,
               float* __restrict__ v, float* __restrict__ dslots, int it)
{
    __shared__ float sm[1536];
    const int tid = threadIdx.x;
    const int bid = blockIdx.x;
    const int b     = bid >> 6;
    const int rbase = (bid & 63) << 4;   // 16 cols per block

    if (it > 0) {
        float tv = dslots[((it - 1) << 6) + (tid & 63)];
#pragma unroll
        for (int off = 32; off; off >>= 1) tv += __shfl_xor(tv, off, 64);
        if (tv * (1.f / 16.f) < THRESH) return;
    }

    float* us   = sm;          // 1024
    float* redm = sm + 1024;   // 256
    float* reds = sm + 1280;   // 256
    ((float4*)us)[tid] = ((const float4*)(u + (size_t)b * Nn))[tid];
    __syncthreads();
    const int jj = tid & 15;
    const int ig = tid >> 4;
    const float* Cb = C + (size_t)b * Nn * Mm + rbase + jj;
    float m = -INFINITY, s = 0.f;
    for (int k = 0; k < 64; ++k) {
        const int i = ig + (k << 4);
        lse_acc(m, s, (us[i] - Cb[(size_t)i * Mm]) * SCALE2);
    }
    redm[tid] = m; reds[tid] = s;
    __syncthreads();
    if (tid < 16) {
        float M2 = redm[tid], S2 = reds[tid];
#pragma unroll
        for (int g = 1; g < 16; ++g)
            lse_comb(M2, S2, redm[(g << 4) + tid], reds[(g << 4) + tid]);
        const float vn = UAB - EPSLN2 * (M2 + log2f(S2));
        float* vp = v + (size_t)b * Mm + rbase + tid;
        const float dd = fabsf(vn - *vp);
        *vp = vn;
        reds[tid] = dd;
    }
    __syncthreads();
    if (tid == 0) {
        float tsum = 0.f;
#pragma unroll
        for (int g = 0; g < 16; ++g) tsum += reds[g];
        atomicAdd(dslots + (it << 6) + (bid & 63), tsum);
    }
}

//==================== cost[b] = sum_ij exp((u_i + v_j - C_ij)/eps) * C_ij
__global__ __launch_bounds__(256)
void cost_kernel(const float* __restrict__ C, const float* __restrict__ u,
                 const float* __restrict__ v, float* __restrict__ out)
{
    __shared__ float sm[4];
    const int tid  = threadIdx.x;
    const int lane = tid & 63;
    const int wv   = tid >> 6;
    const int row  = (blockIdx.x << 2) | wv;
    const int b    = row >> 10;
    const float ui = u[row];
    const float4* v4 = (const float4*)(v + (b << 10));
    const float4* c4 = (const float4*)(C + ((size_t)row << 10));
    float acc = 0.f;
#pragma unroll
    for (int q = 0; q < 4; ++q) {
        const float4 c = c4[lane + (q << 6)];
        const float4 s = v4[lane + (q << 6)];
        acc = fmaf(exp2f((ui + s.x - c.x) * SCALE2), c.x, acc);
        acc = fmaf(exp2f((ui + s.y - c.y) * SCALE2), c.y, acc);
        acc = fmaf(exp2f((ui + s.z - c.z) * SCALE2), c.z, acc);
        acc = fmaf(exp2f((ui + s.w - c.w) * SCALE2), c.w, acc);
    }
#pragma unroll
    for (int off = 32; off; off >>= 1) acc += __shfl_xor(acc, off, 64);
    if (lane == 0) sm[wv] = acc;
    __syncthreads();
    if (tid == 0) atomicAdd(out + b, sm[0] + sm[1] + sm[2] + sm[3]);
}

extern "C" void kernel_launch(void* const* d_in, const int* in_sizes, int n_in,
                              void* d_out, int out_size, void* d_ws, size_t ws_size,
                              hipStream_t stream) {
    const float* x = (const float*)d_in[0];
    const float* y = (const float*)d_in[1];
    float* out = (float*)d_out;

    const size_t nC  = (size_t)Bb * Nn * Mm;   // 16M floats
    const size_t nyT = (size_t)Bb * Dd * Mm;   // 1M floats
    const size_t nu  = (size_t)Bb * Nn;
    const size_t nv  = (size_t)Bb * Mm;
    const size_t nds = (size_t)MAXIT * 64;
    const size_t full_floats = 2 * nC + nyT + nu + nv + nds;
    const bool use_ct = ws_size >= full_floats * sizeof(float);

    float* C  = (float*)d_ws;
    float* CT = use_ct ? (C + nC) : C;          // unused alias in fallback
    float* yT = use_ct ? (CT + nC) : (C + nC);
    float* u  = yT + nyT;
    float* v  = u + nu;
    float* ds = v + nv;

    hipLaunchKernelGGL(init_kernel, dim3(259), dim3(256), 0, stream,
                       y, yT, u, v, ds, out);
    if (use_ct) {
        hipLaunchKernelGGL((cbuild_kernel<true>), dim3(2048), dim3(256), 0, stream,
                           x, yT, C, CT);
        for (int it = 0; it < MAXIT; ++it) {
            hipLaunchKernelGGL(sweep_row, dim3(4096), dim3(256), 0, stream,
                               C, v, u, ds, it);
            hipLaunchKernelGGL(sweep_row, dim3(4096), dim3(256), 0, stream,
                               CT, u, v, ds, it);
        }
    } else {
        hipLaunchKernelGGL((cbuild_kernel<false>), dim3(2048), dim3(256), 0, stream,
                           x, yT, C, CT);
        for (int it = 0; it < MAXIT; ++it) {
            hipLaunchKernelGGL(sweep_row, dim3(4096), dim3(256), 0, stream,
                               C, v, u, ds, it);
            hipLaunchKernelGGL(sweep_col, dim3(1024), dim3(256), 0, stream,
                               C, u, v, ds, it);
        }
    }
    hipLaunchKernelGGL(cost_kernel, dim3(4096), dim3(256), 0, stream,
                       C, u, v, out);
}

// Round 3
// 2725.671 us; speedup vs baseline: 7.6471x; 7.6471x over previous
//
#include <hip/hip_runtime.h>
#include <cmath>

static constexpr int   Bb     = 16;
static constexpr int   Nn     = 1024;
static constexpr int   Mm     = 1024;
static constexpr int   Dd     = 64;
static constexpr int   MAXIT  = 100;
static constexpr float THRESH = 1e-4f;
// (1/eps) * log2(e): scale (v - C) into log2 domain
static constexpr float SCALE2 = 144.26950408889634f;
// eps * ln(2)
static constexpr float EPSLN2 = 0.006931471805599453f;
// eps * log(1/1024 + 1e-8)   (log_a == log_b since N == M)
static constexpr float UAB    = -0.06931461565651f;

// dslots: per-iteration 64 slots, each padded to 16 floats (64 B) to avoid
// same-line atomic contention. 100 * 1024 floats.
static constexpr int SLOT_STRIDE = 16;
static constexpr int SLOTS_PER_IT = 64 * SLOT_STRIDE;   // 1024

__device__ __forceinline__ void lse_acc(float& m, float& s, float a) {
    float nm = fmaxf(m, a);
    s = s * exp2f(m - nm) + exp2f(a - nm);
    m = nm;
}
__device__ __forceinline__ void lse_comb(float& m, float& s, float mo, float so) {
    float nm = fmaxf(m, mo);
    s = s * exp2f(m - nm) + so * exp2f(mo - nm);
    m = nm;
}

//==================== init: transpose y -> yT[b][d][j]; zero u,v,dslots
__global__ __launch_bounds__(256)
void init_kernel(const float* __restrict__ y, float* __restrict__ yT,
                 float* __restrict__ zbase, int zcount4)
{
    __shared__ float sm[64 * 65];
    const int tid = threadIdx.x;
    const int bid = blockIdx.x;
    if (bid < 256) {
        const int b  = bid >> 4;
        const int j0 = (bid & 15) << 6;
        const float4* src = (const float4*)(y + (size_t)(b * Mm + j0) * Dd);
#pragma unroll
        for (int k = 0; k < 4; ++k) {
            const int f4 = tid + (k << 8);
            float4 w = src[f4];
            const int f = f4 << 2;
            float* dst = sm + (f >> 6) * 65 + (f & 63);
            dst[0] = w.x; dst[1] = w.y; dst[2] = w.z; dst[3] = w.w;
        }
        __syncthreads();
        const int jj = tid & 63;
        const int db = tid >> 6;
#pragma unroll
        for (int k = 0; k < 16; ++k) {
            const int d = db + (k << 2);
            yT[(size_t)(b * Dd + d) * Mm + j0 + jj] = sm[jj * 65 + d];
        }
    } else {
        // zero u, v, dslots (contiguous) with 256 blocks, float4 grid-stride
        float4* z = (float4*)zbase;
        for (int k = ((bid - 256) << 8) + tid; k < zcount4; k += 65536)
            z[k] = make_float4(0.f, 0.f, 0.f, 0.f);
    }
}

//==================== build C (and CT): C = ||x||^2 + ||y||^2 - 2 x.y
template <bool USE_CT>
__global__ __launch_bounds__(256)
void cbuild_kernel(const float* __restrict__ x, const float* __restrict__ yT,
                   float* __restrict__ C, float* __restrict__ CT)
{
    __shared__ float sm[2080];
    const int tid = threadIdx.x;
    const int t   = blockIdx.x;     // 2048 tiles
    const int b   = t >> 7;
    const int rm  = t & 127;
    const int i0  = (rm >> 2) << 5;   // 32-row tile
    const int j0  = (rm & 3) << 8;    // 256-col tile
    float* xs2 = sm;                  // 2048: -2*x tile
    float* xn  = sm + 2048;           // 32: x row norms
    const float4* xsrc = (const float4*)(x + (size_t)(b * Nn + i0) * Dd);
#pragma unroll
    for (int k = 0; k < 2; ++k) {
        const int f4 = tid + (k << 8);
        float4 w = xsrc[f4];
        float* dst = xs2 + (f4 << 2);
        dst[0] = -2.f * w.x; dst[1] = -2.f * w.y;
        dst[2] = -2.f * w.z; dst[3] = -2.f * w.w;
    }
    __syncthreads();
    if (tid < 32) {
        float a = 0.f;
        for (int d = 0; d < 64; ++d) { float q = xs2[tid * 64 + d]; a = fmaf(q, q, a); }
        xn[tid] = 0.25f * a;   // (-2x)^2/4 = x^2
    }
    __syncthreads();
    float acc[32];
#pragma unroll
    for (int ii = 0; ii < 32; ++ii) acc[ii] = 0.f;
    float yn = 0.f;
    const float* yTb = yT + (size_t)b * Dd * Mm + j0 + tid;
    for (int d4 = 0; d4 < 64; d4 += 4) {
        const float y0 = yTb[(size_t)(d4 + 0) * Mm];
        const float y1 = yTb[(size_t)(d4 + 1) * Mm];
        const float y2 = yTb[(size_t)(d4 + 2) * Mm];
        const float y3 = yTb[(size_t)(d4 + 3) * Mm];
        yn = fmaf(y0, y0, yn); yn = fmaf(y1, y1, yn);
        yn = fmaf(y2, y2, yn); yn = fmaf(y3, y3, yn);
#pragma unroll
        for (int ii = 0; ii < 32; ++ii) {
            const float4 xq = *(const float4*)(xs2 + ii * 64 + d4);
            acc[ii] = fmaf(xq.x, y0, acc[ii]);
            acc[ii] = fmaf(xq.y, y1, acc[ii]);
            acc[ii] = fmaf(xq.z, y2, acc[ii]);
            acc[ii] = fmaf(xq.w, y3, acc[ii]);
        }
    }
#pragma unroll
    for (int ii = 0; ii < 32; ++ii) acc[ii] += xn[ii] + yn;
    float* Cout = C + (size_t)(b * Nn + i0) * Mm + j0 + tid;
#pragma unroll
    for (int ii = 0; ii < 32; ++ii) Cout[(size_t)ii * Mm] = acc[ii];
    if constexpr (USE_CT) {
        float* CTout = CT + (size_t)(b * Mm + j0 + tid) * Nn + i0;
#pragma unroll
        for (int ii = 0; ii < 32; ii += 4)
            *(float4*)(CTout + ii) =
                make_float4(acc[ii], acc[ii + 1], acc[ii + 2], acc[ii + 3]);
    }
}

//==================== half-sweep: dst_i = UAB - eps*lse_j((src_j - Cmat_ij)/eps)
// One wave per 2 rows; two-pass lse; block-reduced diff -> 1 padded atomic/block.
__global__ __launch_bounds__(256)
void sweep_row(const float* __restrict__ Cmat, const float* __restrict__ src,
               float* __restrict__ dst, float* __restrict__ dslots, int it)
{
    __shared__ float smw[4];
    const int tid  = threadIdx.x;
    const int lane = tid & 63;
    const int wv   = tid >> 6;
    const int row0 = (blockIdx.x << 3) | (wv << 1);   // 2048 blocks * 4 waves * 2 rows
    const int b    = row0 >> 10;

    if (it > 0) {   // frozen? deterministic sum of previous iteration's diff
        float tv = dslots[((it - 1) << 10) + (lane << 4)];
#pragma unroll
        for (int off = 32; off; off >>= 1) tv += __shfl_xor(tv, off, 64);
        if (tv * (1.f / 16.f) < THRESH) return;   // block-uniform
    }

    const float4* s4  = (const float4*)(src + (b << 10));
    const float4* c4a = (const float4*)(Cmat + ((size_t)row0 << 10));
    const float4* c4b = c4a + 256;
    float4 sv[4], ca[4], cb[4];
#pragma unroll
    for (int q = 0; q < 4; ++q) { ca[q] = c4a[lane + (q << 6)]; }
#pragma unroll
    for (int q = 0; q < 4; ++q) { cb[q] = c4b[lane + (q << 6)]; }
#pragma unroll
    for (int q = 0; q < 4; ++q) { sv[q] = s4[lane + (q << 6)]; }

    float a0[16], a1[16];
    float m0 = -INFINITY, m1 = -INFINITY;
#pragma unroll
    for (int q = 0; q < 4; ++q) {
        a0[4 * q + 0] = (sv[q].x - ca[q].x) * SCALE2;
        a0[4 * q + 1] = (sv[q].y - ca[q].y) * SCALE2;
        a0[4 * q + 2] = (sv[q].z - ca[q].z) * SCALE2;
        a0[4 * q + 3] = (sv[q].w - ca[q].w) * SCALE2;
        a1[4 * q + 0] = (sv[q].x - cb[q].x) * SCALE2;
        a1[4 * q + 1] = (sv[q].y - cb[q].y) * SCALE2;
        a1[4 * q + 2] = (sv[q].z - cb[q].z) * SCALE2;
        a1[4 * q + 3] = (sv[q].w - cb[q].w) * SCALE2;
        m0 = fmaxf(m0, fmaxf(fmaxf(a0[4 * q + 0], a0[4 * q + 1]),
                             fmaxf(a0[4 * q + 2], a0[4 * q + 3])));
        m1 = fmaxf(m1, fmaxf(fmaxf(a1[4 * q + 0], a1[4 * q + 1]),
                             fmaxf(a1[4 * q + 2], a1[4 * q + 3])));
    }
#pragma unroll
    for (int off = 32; off; off >>= 1) {
        m0 = fmaxf(m0, __shfl_xor(m0, off, 64));
        m1 = fmaxf(m1, __shfl_xor(m1, off, 64));
    }
    float s0 = 0.f, s1 = 0.f;
#pragma unroll
    for (int k = 0; k < 16; ++k) { s0 += exp2f(a0[k] - m0); s1 += exp2f(a1[k] - m1); }
#pragma unroll
    for (int off = 32; off; off >>= 1) {
        s0 += __shfl_xor(s0, off, 64);
        s1 += __shfl_xor(s1, off, 64);
    }
    if (lane == 0) {
        const float dn0 = UAB - EPSLN2 * (m0 + log2f(s0));
        const float dn1 = UAB - EPSLN2 * (m1 + log2f(s1));
        float* dp = dst + row0;
        const float dd = fabsf(dn0 - dp[0]) + fabsf(dn1 - dp[1]);
        dp[0] = dn0; dp[1] = dn1;
        smw[wv] = dd;
    }
    __syncthreads();
    if (tid == 0) {
        const float bd = smw[0] + smw[1] + smw[2] + smw[3];
        atomicAdd(dslots + (it << 10) + ((blockIdx.x & 63) << 4), bd);
    }
}

//==================== fallback v-update via column reads of C (no CT buffer)
__global__ __launch_bounds__(256)
void sweep_col(const float* __restrict__ C, const float* __restrict__ u,
               float* __restrict__ v, float* __restrict__ dslots, int it)
{
    __shared__ float sm[1536];
    const int tid = threadIdx.x;
    const int bid = blockIdx.x;
    const int b     = bid >> 6;
    const int rbase = (bid & 63) << 4;   // 16 cols per block

    if (it > 0) {
        float tv = dslots[((it - 1) << 10) + ((tid & 63) << 4)];
#pragma unroll
        for (int off = 32; off; off >>= 1) tv += __shfl_xor(tv, off, 64);
        if (tv * (1.f / 16.f) < THRESH) return;
    }

    float* us   = sm;          // 1024
    float* redm = sm + 1024;   // 256
    float* reds = sm + 1280;   // 256
    ((float4*)us)[tid] = ((const float4*)(u + (size_t)b * Nn))[tid];
    __syncthreads();
    const int jj = tid & 15;
    const int ig = tid >> 4;
    const float* Cb = C + (size_t)b * Nn * Mm + rbase + jj;
    float m = -INFINITY, s = 0.f;
    for (int k = 0; k < 64; ++k) {
        const int i = ig + (k << 4);
        lse_acc(m, s, (us[i] - Cb[(size_t)i * Mm]) * SCALE2);
    }
    redm[tid] = m; reds[tid] = s;
    __syncthreads();
    if (tid < 16) {
        float M2 = redm[tid], S2 = reds[tid];
#pragma unroll
        for (int g = 1; g < 16; ++g)
            lse_comb(M2, S2, redm[(g << 4) + tid], reds[(g << 4) + tid]);
        const float vn = UAB - EPSLN2 * (M2 + log2f(S2));
        float* vp = v + (size_t)b * Mm + rbase + tid;
        const float dd = fabsf(vn - *vp);
        *vp = vn;
        reds[tid] = dd;
    }
    __syncthreads();
    if (tid == 0) {
        float tsum = 0.f;
#pragma unroll
        for (int g = 0; g < 16; ++g) tsum += reds[g];
        atomicAdd(dslots + (it << 10) + ((bid & 63) << 4), tsum);
    }
}

//==================== cost partials: one block per 4 rows, plain store
__global__ __launch_bounds__(256)
void cost_kernel(const float* __restrict__ C, const float* __restrict__ u,
                 const float* __restrict__ v, float* __restrict__ cpart)
{
    __shared__ float sm[4];
    const int tid  = threadIdx.x;
    const int lane = tid & 63;
    const int wv   = tid >> 6;
    const int row  = (blockIdx.x << 2) | wv;
    const int b    = row >> 10;
    const float ui = u[row];
    const float4* v4 = (const float4*)(v + (b << 10));
    const float4* c4 = (const float4*)(C + ((size_t)row << 10));
    float acc = 0.f;
#pragma unroll
    for (int q = 0; q < 4; ++q) {
        const float4 c = c4[lane + (q << 6)];
        const float4 s = v4[lane + (q << 6)];
        acc = fmaf(exp2f((ui + s.x - c.x) * SCALE2), c.x, acc);
        acc = fmaf(exp2f((ui + s.y - c.y) * SCALE2), c.y, acc);
        acc = fmaf(exp2f((ui + s.z - c.z) * SCALE2), c.z, acc);
        acc = fmaf(exp2f((ui + s.w - c.w) * SCALE2), c.w, acc);
    }
#pragma unroll
    for (int off = 32; off; off >>= 1) acc += __shfl_xor(acc, off, 64);
    if (lane == 0) sm[wv] = acc;
    __syncthreads();
    if (tid == 0) cpart[blockIdx.x] = sm[0] + sm[1] + sm[2] + sm[3];
}

//==================== finalize: out[b] = sum of 256 partials (16 blocks)
__global__ __launch_bounds__(256)
void cost_fin(const float* __restrict__ cpart, float* __restrict__ out)
{
    __shared__ float sm[4];
    const int tid  = threadIdx.x;
    const int lane = tid & 63;
    const int wv   = tid >> 6;
    float vpt = cpart[(blockIdx.x << 8) + tid];
#pragma unroll
    for (int off = 32; off; off >>= 1) vpt += __shfl_xor(vpt, off, 64);
    if (lane == 0) sm[wv] = vpt;
    __syncthreads();
    if (tid == 0) out[blockIdx.x] = sm[0] + sm[1] + sm[2] + sm[3];
}

extern "C" void kernel_launch(void* const* d_in, const int* in_sizes, int n_in,
                              void* d_out, int out_size, void* d_ws, size_t ws_size,
                              hipStream_t stream) {
    const float* x = (const float*)d_in[0];
    const float* y = (const float*)d_in[1];
    float* out = (float*)d_out;

    const size_t nC  = (size_t)Bb * Nn * Mm;            // 16M floats
    const size_t nyT = (size_t)Bb * Dd * Mm;            // 1M floats
    const size_t nu  = (size_t)Bb * Nn;
    const size_t nv  = (size_t)Bb * Mm;
    const size_t nds = (size_t)MAXIT * SLOTS_PER_IT;    // 102400
    const size_t ncp = 4096;
    const size_t full_floats = 2 * nC + nyT + nu + nv + nds + ncp;
    const bool use_ct = ws_size >= full_floats * sizeof(float);

    float* C  = (float*)d_ws;
    float* CT = use_ct ? (C + nC) : C;          // unused alias in fallback
    float* yT = use_ct ? (CT + nC) : (C + nC);
    float* u  = yT + nyT;
    float* v  = u + nu;
    float* ds = v + nv;
    float* cp = ds + nds;

    // zero u, v, ds (contiguous): count in float4s
    const int zcount4 = (int)((nu + nv + nds) >> 2);

    hipLaunchKernelGGL(init_kernel, dim3(512), dim3(256), 0, stream,
                       y, yT, u, zcount4);
    if (use_ct) {
        hipLaunchKernelGGL((cbuild_kernel<true>), dim3(2048), dim3(256), 0, stream,
                           x, yT, C, CT);
        for (int it = 0; it < MAXIT; ++it) {
            hipLaunchKernelGGL(sweep_row, dim3(2048), dim3(256), 0, stream,
                               C, v, u, ds, it);
            hipLaunchKernelGGL(sweep_row, dim3(2048), dim3(256), 0, stream,
                               CT, u, v, ds, it);
        }
    } else {
        hipLaunchKernelGGL((cbuild_kernel<false>), dim3(2048), dim3(256), 0, stream,
                           x, yT, C, CT);
        for (int it = 0; it < MAXIT; ++it) {
            hipLaunchKernelGGL(sweep_row, dim3(2048), dim3(256), 0, stream,
                               C, v, u, ds, it);
            hipLaunchKernelGGL(sweep_col, dim3(1024), dim3(256), 0, stream,
                               C, u, v, ds, it);
        }
    }
    hipLaunchKernelGGL(cost_kernel, dim3(4096), dim3(256), 0, stream,
                       C, u, v, cp);
    hipLaunchKernelGGL(cost_fin, dim3(16), dim3(256), 0, stream, cp, out);
}

// Round 4
// 2062.366 us; speedup vs baseline: 10.1065x; 1.3216x over previous
//
#include <hip/hip_runtime.h>
#include <hip/hip_fp16.h>
#include <cmath>

static constexpr int   Bb     = 16;
static constexpr int   Nn     = 1024;
static constexpr int   Mm     = 1024;
static constexpr int   Dd     = 64;
static constexpr int   MAXIT  = 100;
static constexpr float THRESH = 1e-4f;
// (1/eps) * log2(e): scale (v - C) into log2 domain
static constexpr float SCALE2 = 144.26950408889634f;
// eps * ln(2)
static constexpr float EPSLN2 = 0.006931471805599453f;
// eps * log(1/1024 + 1e-8)   (log_a == log_b since N == M)
static constexpr float UAB    = -0.06931461565651f;

// dslots: per-iteration 64 slots, each padded to 16 floats (64 B line)
static constexpr int SLOTS_PER_IT = 1024;

__device__ __forceinline__ void lse_acc(float& m, float& s, float a) {
    float nm = fmaxf(m, a);
    s = s * exp2f(m - nm) + exp2f(a - nm);
    m = nm;
}
__device__ __forceinline__ void lse_comb(float& m, float& s, float mo, float so) {
    float nm = fmaxf(m, mo);
    s = s * exp2f(m - nm) + so * exp2f(mo - nm);
    m = nm;
}
__device__ __forceinline__ void unpack8(const float4 w, float* out) {
    const __half2* h = (const __half2*)&w;
#pragma unroll
    for (int e = 0; e < 4; ++e) {
        float2 f = __half22float2(h[e]);
        out[2 * e]     = f.x;
        out[2 * e + 1] = f.y;
    }
}

//==================== init: transpose y -> yT[b][d][j]; zero u,v,dslots
__global__ __launch_bounds__(256)
void init_kernel(const float* __restrict__ y, float* __restrict__ yT,
                 float* __restrict__ zbase, int zcount4)
{
    __shared__ float sm[64 * 65];
    const int tid = threadIdx.x;
    const int bid = blockIdx.x;
    if (bid < 256) {
        const int b  = bid >> 4;
        const int j0 = (bid & 15) << 6;
        const float4* src = (const float4*)(y + (size_t)(b * Mm + j0) * Dd);
#pragma unroll
        for (int k = 0; k < 4; ++k) {
            const int f4 = tid + (k << 8);
            float4 w = src[f4];
            const int f = f4 << 2;
            float* dst = sm + (f >> 6) * 65 + (f & 63);
            dst[0] = w.x; dst[1] = w.y; dst[2] = w.z; dst[3] = w.w;
        }
        __syncthreads();
        const int jj = tid & 63;
        const int db = tid >> 6;
#pragma unroll
        for (int k = 0; k < 16; ++k) {
            const int d = db + (k << 2);
            yT[(size_t)(b * Dd + d) * Mm + j0 + jj] = sm[jj * 65 + d];
        }
    } else {
        float4* z = (float4*)zbase;
        for (int k = ((bid - 256) << 8) + tid; k < zcount4; k += 65536)
            z[k] = make_float4(0.f, 0.f, 0.f, 0.f);
    }
}

//==================== build C (and CT) in fp16: C = ||x||^2 + ||y||^2 - 2 x.y
template <bool USE_CT>
__global__ __launch_bounds__(256)
void cbuild_kernel(const float* __restrict__ x, const float* __restrict__ yT,
                   __half* __restrict__ C, __half* __restrict__ CT)
{
    __shared__ float sm[2080];
    const int tid = threadIdx.x;
    const int t   = blockIdx.x;       // 2048 tiles
    const int b   = t >> 7;
    const int rm  = t & 127;
    const int i0  = (rm >> 2) << 5;   // 32-row tile
    const int j0  = (rm & 3) << 8;    // 256-col tile
    float* xs2 = sm;                  // 2048: -2*x tile
    float* xn  = sm + 2048;           // 32: x row norms
    const float4* xsrc = (const float4*)(x + (size_t)(b * Nn + i0) * Dd);
#pragma unroll
    for (int k = 0; k < 2; ++k) {
        const int f4 = tid + (k << 8);
        float4 w = xsrc[f4];
        float* dst = xs2 + (f4 << 2);
        dst[0] = -2.f * w.x; dst[1] = -2.f * w.y;
        dst[2] = -2.f * w.z; dst[3] = -2.f * w.w;
    }
    __syncthreads();
    if (tid < 32) {
        float a = 0.f;
        for (int d = 0; d < 64; ++d) { float q = xs2[tid * 64 + d]; a = fmaf(q, q, a); }
        xn[tid] = 0.25f * a;   // (-2x)^2/4 = x^2
    }
    __syncthreads();
    float acc[32];
#pragma unroll
    for (int ii = 0; ii < 32; ++ii) acc[ii] = 0.f;
    float yn = 0.f;
    const float* yTb = yT + (size_t)b * Dd * Mm + j0 + tid;
    for (int d4 = 0; d4 < 64; d4 += 4) {
        const float y0 = yTb[(size_t)(d4 + 0) * Mm];
        const float y1 = yTb[(size_t)(d4 + 1) * Mm];
        const float y2 = yTb[(size_t)(d4 + 2) * Mm];
        const float y3 = yTb[(size_t)(d4 + 3) * Mm];
        yn = fmaf(y0, y0, yn); yn = fmaf(y1, y1, yn);
        yn = fmaf(y2, y2, yn); yn = fmaf(y3, y3, yn);
#pragma unroll
        for (int ii = 0; ii < 32; ++ii) {
            const float4 xq = *(const float4*)(xs2 + ii * 64 + d4);
            acc[ii] = fmaf(xq.x, y0, acc[ii]);
            acc[ii] = fmaf(xq.y, y1, acc[ii]);
            acc[ii] = fmaf(xq.z, y2, acc[ii]);
            acc[ii] = fmaf(xq.w, y3, acc[ii]);
        }
    }
#pragma unroll
    for (int ii = 0; ii < 32; ++ii) acc[ii] += xn[ii] + yn;
    __half* Cout = C + (size_t)(b * Nn + i0) * Mm + j0 + tid;
#pragma unroll
    for (int ii = 0; ii < 32; ++ii) Cout[(size_t)ii << 10] = __float2half(acc[ii]);
    if constexpr (USE_CT) {
        __half* CTout = CT + ((size_t)((b << 10) + j0 + tid) << 10) + i0;
#pragma unroll
        for (int g = 0; g < 4; ++g) {
            float4 w;
            __half2* hp = (__half2*)&w;
            hp[0] = __floats2half2_rn(acc[8 * g + 0], acc[8 * g + 1]);
            hp[1] = __floats2half2_rn(acc[8 * g + 2], acc[8 * g + 3]);
            hp[2] = __floats2half2_rn(acc[8 * g + 4], acc[8 * g + 5]);
            hp[3] = __floats2half2_rn(acc[8 * g + 6], acc[8 * g + 7]);
            ((float4*)CTout)[g] = w;
        }
    }
}

//==================== half-sweep: dst_i = UAB - eps*lse_j((src_j - Cmat_ij)/eps)
// Cmat fp16 row-major for this phase. 2 rows per wave; two-pass lse;
// block-reduced diff -> 1 padded atomic per block.
__global__ __launch_bounds__(256)
void sweep_row(const __half* __restrict__ Cmat, const float* __restrict__ src,
               float* __restrict__ dst, float* __restrict__ dslots, int it)
{
    __shared__ float smw[4];
    const int tid  = threadIdx.x;
    const int lane = tid & 63;
    const int wv   = tid >> 6;
    const int row0 = (blockIdx.x << 3) | (wv << 1);   // 2048 blocks * 4 waves * 2 rows
    const int b    = row0 >> 10;

    if (it > 0) {   // frozen? deterministic sum of previous iteration's diff
        float tv = dslots[((it - 1) << 10) + (lane << 4)];
#pragma unroll
        for (int off = 32; off; off >>= 1) tv += __shfl_xor(tv, off, 64);
        if (tv * (1.f / 16.f) < THRESH) return;   // block-uniform
    }

    // src values * SCALE2 for this lane's 16 columns:
    // q=0: j = lane*8 .. +7 ; q=1: j = 512 + lane*8 .. +7
    const float4* s4 = (const float4*)(src + (b << 10));
    float4 sv0 = s4[(lane << 1)];
    float4 sv1 = s4[(lane << 1) + 1];
    float4 sv2 = s4[128 + (lane << 1)];
    float4 sv3 = s4[129 + (lane << 1)];
    float svs[16];
    svs[0] = sv0.x * SCALE2; svs[1] = sv0.y * SCALE2;
    svs[2] = sv0.z * SCALE2; svs[3] = sv0.w * SCALE2;
    svs[4] = sv1.x * SCALE2; svs[5] = sv1.y * SCALE2;
    svs[6] = sv1.z * SCALE2; svs[7] = sv1.w * SCALE2;
    svs[8]  = sv2.x * SCALE2; svs[9]  = sv2.y * SCALE2;
    svs[10] = sv2.z * SCALE2; svs[11] = sv2.w * SCALE2;
    svs[12] = sv3.x * SCALE2; svs[13] = sv3.y * SCALE2;
    svs[14] = sv3.z * SCALE2; svs[15] = sv3.w * SCALE2;

    // C rows (fp16): row stride = 128 float4
    const float4* c4 = (const float4*)(Cmat + ((size_t)row0 << 10));
    float4 ca0 = c4[lane];        // row0, j = lane*8..
    float4 ca1 = c4[64 + lane];   // row0, j = 512 + lane*8..
    float4 cb0 = c4[128 + lane];  // row1
    float4 cb1 = c4[192 + lane];

    float cf[32];
    unpack8(ca0, cf);      unpack8(ca1, cf + 8);
    unpack8(cb0, cf + 16); unpack8(cb1, cf + 24);

    float a0[16], a1[16];
    float m0 = -INFINITY, m1 = -INFINITY;
#pragma unroll
    for (int k = 0; k < 16; ++k) {
        a0[k] = fmaf(cf[k],      -SCALE2, svs[k]);
        a1[k] = fmaf(cf[16 + k], -SCALE2, svs[k]);
        m0 = fmaxf(m0, a0[k]);
        m1 = fmaxf(m1, a1[k]);
    }
#pragma unroll
    for (int off = 32; off; off >>= 1) {
        m0 = fmaxf(m0, __shfl_xor(m0, off, 64));
        m1 = fmaxf(m1, __shfl_xor(m1, off, 64));
    }
    float s0 = 0.f, s1 = 0.f;
#pragma unroll
    for (int k = 0; k < 16; ++k) { s0 += exp2f(a0[k] - m0); s1 += exp2f(a1[k] - m1); }
#pragma unroll
    for (int off = 32; off; off >>= 1) {
        s0 += __shfl_xor(s0, off, 64);
        s1 += __shfl_xor(s1, off, 64);
    }
    if (lane == 0) {
        const float dn0 = UAB - EPSLN2 * (m0 + log2f(s0));
        const float dn1 = UAB - EPSLN2 * (m1 + log2f(s1));
        float* dp = dst + row0;
        const float dd = fabsf(dn0 - dp[0]) + fabsf(dn1 - dp[1]);
        dp[0] = dn0; dp[1] = dn1;
        smw[wv] = dd;
    }
    __syncthreads();
    if (tid == 0) {
        const float bd = smw[0] + smw[1] + smw[2] + smw[3];
        atomicAdd(dslots + (it << 10) + ((blockIdx.x & 63) << 4), bd);
    }
}

//==================== fallback v-update via column reads of C (no CT buffer)
__global__ __launch_bounds__(256)
void sweep_col(const __half* __restrict__ C, const float* __restrict__ u,
               float* __restrict__ v, float* __restrict__ dslots, int it)
{
    __shared__ float sm[1536];
    const int tid = threadIdx.x;
    const int bid = blockIdx.x;
    const int b     = bid >> 6;
    const int rbase = (bid & 63) << 4;   // 16 cols per block

    if (it > 0) {
        float tv = dslots[((it - 1) << 10) + ((tid & 63) << 4)];
#pragma unroll
        for (int off = 32; off; off >>= 1) tv += __shfl_xor(tv, off, 64);
        if (tv * (1.f / 16.f) < THRESH) return;
    }

    float* us   = sm;          // 1024
    float* redm = sm + 1024;   // 256
    float* reds = sm + 1280;   // 256
    ((float4*)us)[tid] = ((const float4*)(u + (size_t)b * Nn))[tid];
    __syncthreads();
    const int jj = tid & 15;
    const int ig = tid >> 4;
    const __half* Cb = C + (size_t)b * Nn * Mm + rbase + jj;
    float m = -INFINITY, s = 0.f;
    for (int k = 0; k < 64; ++k) {
        const int i = ig + (k << 4);
        lse_acc(m, s, (us[i] - __half2float(Cb[(size_t)i << 10])) * SCALE2);
    }
    redm[tid] = m; reds[tid] = s;
    __syncthreads();
    if (tid < 16) {
        float M2 = redm[tid], S2 = reds[tid];
#pragma unroll
        for (int g = 1; g < 16; ++g)
            lse_comb(M2, S2, redm[(g << 4) + tid], reds[(g << 4) + tid]);
        const float vn = UAB - EPSLN2 * (M2 + log2f(S2));
        float* vp = v + (size_t)b * Mm + rbase + tid;
        const float dd = fabsf(vn - *vp);
        *vp = vn;
        reds[tid] = dd;
    }
    __syncthreads();
    if (tid == 0) {
        float tsum = 0.f;
#pragma unroll
        for (int g = 0; g < 16; ++g) tsum += reds[g];
        atomicAdd(dslots + (it << 10) + ((bid & 63) << 4), tsum);
    }
}

//==================== cost partials: one block per 4 rows, plain store
__global__ __launch_bounds__(256)
void cost_kernel(const __half* __restrict__ C, const float* __restrict__ u,
                 const float* __restrict__ v, float* __restrict__ cpart)
{
    __shared__ float sm[4];
    const int tid  = threadIdx.x;
    const int lane = tid & 63;
    const int wv   = tid >> 6;
    const int row  = (blockIdx.x << 2) | wv;
    const int b    = row >> 10;
    const float ui = u[row];

    const float4* s4 = (const float4*)(v + (b << 10));
    float4 sv0 = s4[(lane << 1)];
    float4 sv1 = s4[(lane << 1) + 1];
    float4 sv2 = s4[128 + (lane << 1)];
    float4 sv3 = s4[129 + (lane << 1)];
    float vv[16];
    vv[0] = sv0.x; vv[1] = sv0.y; vv[2]  = sv0.z; vv[3]  = sv0.w;
    vv[4] = sv1.x; vv[5] = sv1.y; vv[6]  = sv1.z; vv[7]  = sv1.w;
    vv[8] = sv2.x; vv[9] = sv2.y; vv[10] = sv2.z; vv[11] = sv2.w;
    vv[12] = sv3.x; vv[13] = sv3.y; vv[14] = sv3.z; vv[15] = sv3.w;

    const float4* c4 = (const float4*)(C + ((size_t)row << 10));
    float cf[16];
    unpack8(c4[lane], cf);
    unpack8(c4[64 + lane], cf + 8);

    float acc = 0.f;
#pragma unroll
    for (int k = 0; k < 16; ++k)
        acc = fmaf(exp2f((ui + vv[k] - cf[k]) * SCALE2), cf[k], acc);
#pragma unroll
    for (int off = 32; off; off >>= 1) acc += __shfl_xor(acc, off, 64);
    if (lane == 0) sm[wv] = acc;
    __syncthreads();
    if (tid == 0) cpart[blockIdx.x] = sm[0] + sm[1] + sm[2] + sm[3];
}

//==================== finalize: out[b] = sum of 256 partials (16 blocks)
__global__ __launch_bounds__(256)
void cost_fin(const float* __restrict__ cpart, float* __restrict__ out)
{
    __shared__ float sm[4];
    const int tid  = threadIdx.x;
    const int lane = tid & 63;
    const int wv   = tid >> 6;
    float vpt = cpart[(blockIdx.x << 8) + tid];
#pragma unroll
    for (int off = 32; off; off >>= 1) vpt += __shfl_xor(vpt, off, 64);
    if (lane == 0) sm[wv] = vpt;
    __syncthreads();
    if (tid == 0) out[blockIdx.x] = sm[0] + sm[1] + sm[2] + sm[3];
}

extern "C" void kernel_launch(void* const* d_in, const int* in_sizes, int n_in,
                              void* d_out, int out_size, void* d_ws, size_t ws_size,
                              hipStream_t stream) {
    const float* x = (const float*)d_in[0];
    const float* y = (const float*)d_in[1];
    float* out = (float*)d_out;

    const size_t nCh = (size_t)Bb * Nn * Mm;            // 16M halves = 32 MB
    const size_t nyT = (size_t)Bb * Dd * Mm;            // 1M floats
    const size_t nu  = (size_t)Bb * Nn;
    const size_t nv  = (size_t)Bb * Mm;
    const size_t nds = (size_t)MAXIT * SLOTS_PER_IT;    // 102400 floats
    const size_t ncp = 4096;
    const size_t bytes_full = 2 * nCh * sizeof(__half) +
                              (nyT + nu + nv + nds + ncp) * sizeof(float);
    const bool use_ct = ws_size >= bytes_full;

    __half* C  = (__half*)d_ws;
    __half* CT = use_ct ? (C + nCh) : C;        // unused alias in fallback
    float*  yT = use_ct ? (float*)(CT + nCh) : (float*)(C + nCh);
    float*  u  = yT + nyT;
    float*  v  = u + nu;
    float*  ds = v + nv;
    float*  cp = ds + nds;

    const int zcount4 = (int)((nu + nv + nds) >> 2);

    hipLaunchKernelGGL(init_kernel, dim3(512), dim3(256), 0, stream,
                       y, yT, u, zcount4);
    if (use_ct) {
        hipLaunchKernelGGL((cbuild_kernel<true>), dim3(2048), dim3(256), 0, stream,
                           x, yT, C, CT);
        for (int it = 0; it < MAXIT; ++it) {
            hipLaunchKernelGGL(sweep_row, dim3(2048), dim3(256), 0, stream,
                               C, v, u, ds, it);
            hipLaunchKernelGGL(sweep_row, dim3(2048), dim3(256), 0, stream,
                               CT, u, v, ds, it);
        }
    } else {
        hipLaunchKernelGGL((cbuild_kernel<false>), dim3(2048), dim3(256), 0, stream,
                           x, yT, C, CT);
        for (int it = 0; it < MAXIT; ++it) {
            hipLaunchKernelGGL(sweep_row, dim3(2048), dim3(256), 0, stream,
                               C, v, u, ds, it);
            hipLaunchKernelGGL(sweep_col, dim3(1024), dim3(256), 0, stream,
                               C, u, v, ds, it);
        }
    }
    hipLaunchKernelGGL(cost_kernel, dim3(4096), dim3(256), 0, stream,
                       C, u, v, cp);
    hipLaunchKernelGGL(cost_fin, dim3(16), dim3(256), 0, stream, cp, out);
}